// Round 7
// baseline (442.890 us; speedup 1.0000x reference)
//
#include <hip/hip_runtime.h>

// MemoryReader: B=4, CK=64, N=8192, M=1024, CV=512. Inputs fp32, output fp32.
// logits s[n,m] = (2*mk.qk - |mk|^2)/8; softmax over n; out = mv @ P.
// R6 passed (absmax 5.9e-3) but k_main was latency-bound: 1 block/CU, all pipes
// <15% busy. R7: 8-way N-split -> 2048 blocks (8/CU, 100% wave occupancy),
// k_main emits unnormalized partials + free partial denominators (k_denom
// deleted), k_reduce combines. LDS pitch 72 kept (b128 16B-aligned, 2-way=free).

typedef unsigned short ushort_t;
typedef unsigned int uint_t;
typedef __attribute__((ext_vector_type(8))) short short8;
typedef __attribute__((ext_vector_type(4))) float floatx4;

#define MFMA16(a, b, c) __builtin_amdgcn_mfma_f32_16x16x32_bf16((a), (b), (c), 0, 0, 0)

__device__ __forceinline__ ushort_t f2b(float f) {
    uint_t b = __float_as_uint(f);
    b += 0x7FFFu + ((b >> 16) & 1u);   // RNE to bf16
    return (ushort_t)(b >> 16);
}

#define BB 4
#define CK 64
#define NN 8192
#define MM 1024
#define CV 512
#define NS 8          // n-splits
#define NSTEPS 16     // 64-token steps per split (8192/8/64)

// ---- module-scope scratch (fully rewritten every call) ----
__device__ __align__(16) ushort_t g_mkT[BB * NN * CK];        // 4 MiB  bf16 mk^T [b][n][c]
__device__ __align__(16) float    g_asq8[BB * NN];            // 128 KiB (sum mk^2)/8
__device__ __align__(16) ushort_t g_mvb[BB * CV * NN];        // 32 MiB bf16 mv [b][c][n]
__device__ __align__(16) float    g_pacc[NS * BB * CV * MM];  // 64 MiB partial numerators
__device__ __align__(16) float    g_pden[NS * BB * MM];       // 128 KiB partial denoms

// ---------------------------------------------------------------------------
// K0: g_mkT[b][n][c] = bf16(mk[b][c][n]); g_asq8 = (sum_c mk^2)/8 in fp32.
// ---------------------------------------------------------------------------
__global__ __launch_bounds__(256) void k_prep(const float* __restrict__ mk) {
    int t = blockIdx.x * 256 + threadIdx.x;   // 0 .. B*N-1
    int b = t >> 13;
    int n = t & (NN - 1);
    const float* src = mk + (size_t)b * CK * NN + n;
    ushort_t* dst = g_mkT + (size_t)t * CK;
    float acc = 0.f;
#pragma unroll
    for (int g = 0; g < 8; g++) {
        float f[8];
#pragma unroll
        for (int i = 0; i < 8; i++) {
            f[i] = src[(size_t)(g * 8 + i) * NN];
            acc += f[i] * f[i];
        }
        uint4 q;
        q.x = (uint_t)f2b(f[0]) | ((uint_t)f2b(f[1]) << 16);
        q.y = (uint_t)f2b(f[2]) | ((uint_t)f2b(f[3]) << 16);
        q.z = (uint_t)f2b(f[4]) | ((uint_t)f2b(f[5]) << 16);
        q.w = (uint_t)f2b(f[6]) | ((uint_t)f2b(f[7]) << 16);
        *(uint4*)(dst + g * 8) = q;
    }
    g_asq8[t] = acc * 0.125f;
}

// ---------------------------------------------------------------------------
// K0b: g_mvb = bf16(mv), flat, 8 elems/thread.
// ---------------------------------------------------------------------------
__global__ __launch_bounds__(256) void k_mvconv(const float* __restrict__ mv) {
    size_t t = (size_t)blockIdx.x * 256 + threadIdx.x;
    const float4* s = (const float4*)mv + t * 2;
    float4 x = s[0], y = s[1];
    uint4 q;
    q.x = (uint_t)f2b(x.x) | ((uint_t)f2b(x.y) << 16);
    q.y = (uint_t)f2b(x.z) | ((uint_t)f2b(x.w) << 16);
    q.z = (uint_t)f2b(y.x) | ((uint_t)f2b(y.y) << 16);
    q.w = (uint_t)f2b(y.z) | ((uint_t)f2b(y.w) << 16);
    ((uint4*)g_mvb)[t] = q;
}

// ---------------------------------------------------------------------------
// K1: fused scores+readout partials. grid 2048 = b(4) x cs(4) x mt16(16) x ns(8).
// bx encoding keeps bx%8 constant per (b,cs) -> one XCD serves one 2 MiB mv
// slice (L2 locality heuristic). 8 blocks/CU -> 32 waves/CU.
// Per 64-token n-step: GEMM1 (MFMA) -> exp -> P bf16 to LDS (+ dpart denom
// accum), barrier, GEMM2 (MFMA, mv direct 16B loads), barrier.
// Layouts (m89/m91): A[m=lane&15][k=quad*8+j], B[n=lane&15][k=quad*8+j],
// D col=lane&15 (B row), row=quad*4+reg (A row).
// ---------------------------------------------------------------------------
__global__ __launch_bounds__(256, 8) void k_main(const float* __restrict__ qk) {
    __shared__ __align__(16) ushort_t lds_p[64 * 72];

    int bx = blockIdx.x;
    int half = bx >> 10;
    int low = bx & 1023;
    int g = half * 8 + (low & 7);    // 0..15 = b*4+cs
    int inner = low >> 3;            // 0..127
    int mt16 = inner >> 3;           // 0..15
    int ns = inner & 7;              // 0..7
    int b = g >> 2;
    int cs = g & 3;
    int c0 = cs * 128;
    int m0 = mt16 * 64;
    int nstart = ns * (NN / NS);

    int tid = threadIdx.x;
    int w = tid >> 6;
    int lane = tid & 63;
    int quad = lane >> 4;
    int l15 = lane & 15;

    // Q fragments for this wave's 16 m-rows (K=64, 2 chunks), held all loop.
    int mrow = m0 + w * 16 + l15;
    short8 aq0, aq1;
#pragma unroll
    for (int j = 0; j < 8; j++) {
        aq0[j] = (short)f2b(qk[(size_t)(b * CK + quad * 8 + j) * MM + mrow]);
        aq1[j] = (short)f2b(qk[(size_t)(b * CK + 32 + quad * 8 + j) * MM + mrow]);
    }

    floatx4 acc[2][4];
#pragma unroll
    for (int i = 0; i < 2; i++)
#pragma unroll
        for (int j = 0; j < 4; j++)
            acc[i][j] = (floatx4){0.f, 0.f, 0.f, 0.f};

    float dpart[4] = {0.f, 0.f, 0.f, 0.f};   // partial denom, rows mbase..+3
    int mbase = w * 16 + quad * 4;

    for (int step = 0; step < NSTEPS; step++) {
        int n0 = nstart + step * 64;
        // ---- GEMM1: scores -> exp -> P(bf16) in LDS; accumulate dpart ----
#pragma unroll
        for (int nt = 0; nt < 4; nt++) {
            int n_l = n0 + nt * 16 + l15;
            const ushort_t* kr = g_mkT + (size_t)(b * NN + n_l) * CK + quad * 8;
            short8 kb0 = *(const short8*)kr;
            short8 kb1 = *(const short8*)(kr + 32);
            floatx4 d = {0.f, 0.f, 0.f, 0.f};
            d = MFMA16(aq0, kb0, d);
            d = MFMA16(aq1, kb1, d);
            float sa = g_asq8[b * NN + n_l];
#pragma unroll
            for (int r = 0; r < 4; r++) {
                float p = __expf(d[r] * 0.25f - sa);
                dpart[r] += p;
                lds_p[(mbase + r) * 72 + nt * 16 + l15] = f2b(p);
            }
        }
        __syncthreads();

        // ---- GEMM2: acc += V @ P^T ----
#pragma unroll
        for (int kc = 0; kc < 2; kc++) {
            short8 pb[4];
#pragma unroll
            for (int mt = 0; mt < 4; mt++)
                pb[mt] = *(const short8*)&lds_p[(mt * 16 + l15) * 72 + kc * 32 + quad * 8];
#pragma unroll
            for (int ctl = 0; ctl < 2; ctl++) {
                size_t vidx = (size_t)(b * CV + c0 + w * 32 + ctl * 16 + l15) * NN
                              + n0 + kc * 32 + quad * 8;
                short8 va = *(const short8*)(g_mvb + vidx);
#pragma unroll
                for (int mt = 0; mt < 4; mt++)
                    acc[ctl][mt] = MFMA16(va, pb[mt], acc[ctl][mt]);
            }
        }
        __syncthreads();
    }

    // ---- epilogue: unnormalized partials to g_pacc; cs==0 writes g_pden ----
#pragma unroll
    for (int mt = 0; mt < 4; mt++) {
#pragma unroll
        for (int ctl = 0; ctl < 2; ctl++) {
            int cbase = c0 + w * 32 + ctl * 16 + quad * 4;
            size_t obase = (size_t)((ns * BB + b) * CV + cbase) * MM + m0 + mt * 16 + l15;
            g_pacc[obase + 0 * MM] = acc[ctl][mt][0];
            g_pacc[obase + 1 * MM] = acc[ctl][mt][1];
            g_pacc[obase + 2 * MM] = acc[ctl][mt][2];
            g_pacc[obase + 3 * MM] = acc[ctl][mt][3];
        }
    }
    // reduce dpart across the 16 lanes (n) of each quad
#pragma unroll
    for (int off = 1; off < 16; off <<= 1) {
#pragma unroll
        for (int r = 0; r < 4; r++) dpart[r] += __shfl_xor(dpart[r], off, 64);
    }
    if (cs == 0 && l15 == 0) {
        float* dp = g_pden + (size_t)(ns * BB + b) * MM + m0 + w * 16 + quad * 4;
        dp[0] = dpart[0];
        dp[1] = dpart[1];
        dp[2] = dpart[2];
        dp[3] = dpart[3];
    }
}

// ---------------------------------------------------------------------------
// K2: out[b][c][m] = sum_s pacc / sum_s pden. float4 over m; 2048 blocks.
// ---------------------------------------------------------------------------
__global__ __launch_bounds__(256) void k_reduce(float* __restrict__ out) {
    int row = blockIdx.x;            // 0..2047 = b*512 + c
    int b = row >> 9;
    int m4 = threadIdx.x;            // 0..255 -> m = m4*4
    float4 num = {0.f, 0.f, 0.f, 0.f};
    float4 den = {0.f, 0.f, 0.f, 0.f};
#pragma unroll
    for (int s = 0; s < NS; s++) {
        float4 a = *(const float4*)&g_pacc[((size_t)(s * BB) * CV * MM) + (size_t)row * MM + m4 * 4];
        float4 d = *(const float4*)&g_pden[(size_t)(s * BB + b) * MM + m4 * 4];
        num.x += a.x; num.y += a.y; num.z += a.z; num.w += a.w;
        den.x += d.x; den.y += d.y; den.z += d.z; den.w += d.w;
    }
    float4 o;
    o.x = num.x / den.x;
    o.y = num.y / den.y;
    o.z = num.z / den.z;
    o.w = num.w / den.w;
    *(float4*)&out[(size_t)row * MM + m4 * 4] = o;
}

// ---------------------------------------------------------------------------
// launch — inputs identified BY SIZE.
// ---------------------------------------------------------------------------
extern "C" void kernel_launch(void* const* d_in, const int* in_sizes, int n_in,
                              void* d_out, int out_size, void* d_ws, size_t ws_size,
                              hipStream_t stream) {
    const float* mk = nullptr;   // 2,097,152
    const float* qk = nullptr;   //   262,144
    const float* mv = nullptr;   // 16,777,216
    for (int i = 0; i < n_in; i++) {
        if (in_sizes[i] == BB * CK * NN)      mk = (const float*)d_in[i];
        else if (in_sizes[i] == BB * CK * MM) qk = (const float*)d_in[i];
        else if (in_sizes[i] == BB * CV * NN) mv = (const float*)d_in[i];
    }
    float* out = (float*)d_out;
    (void)d_ws; (void)ws_size; (void)out_size;

    const size_t mv_elems = (size_t)BB * CV * NN;

    k_prep<<<(BB * NN) / 256, 256, 0, stream>>>(mk);
    k_mvconv<<<(int)(mv_elems / (8 * 256)), 256, 0, stream>>>(mv);
    k_main<<<BB * 4 * 16 * NS, 256, 0, stream>>>(qk);
    k_reduce<<<BB * CV, 256, 0, stream>>>(out);
}

// Round 8
// 292.428 us; speedup vs baseline: 1.5145x; 1.5145x over previous
//
#include <hip/hip_runtime.h>

// MemoryReader: B=4, CK=64, N=8192, M=1024, CV=512. Inputs fp32, output fp32.
// logits s[n,m] = (2*mk.qk - |mk|^2)/8; softmax over n; out = mv @ P.
// R6: 292us k_main, latency-bound (4 waves/CU, all pipes <15%), FETCH 27MB.
// R7: N-split -> 78% occupancy but L2 thrash (FETCH 430MB) + pacc round-trip: 330us.
// R8: keep R6's lockstep streaming (no N-split), get 8 waves/CU via cs=8 (grid 512,
// 2 blocks/CU); K-tile staged once per block via async global_load_lds (dbuf,
// [cq][n] chunk layout, 2-way-max banks); denominator computed in-block for free
// (k_denom/k_reduce deleted); direct fp32 output.

typedef unsigned short ushort_t;
typedef unsigned int uint_t;
typedef __attribute__((ext_vector_type(8))) short short8;
typedef __attribute__((ext_vector_type(4))) float floatx4;

#define MFMA16(a, b, c) __builtin_amdgcn_mfma_f32_16x16x32_bf16((a), (b), (c), 0, 0, 0)

__device__ __forceinline__ ushort_t f2b(float f) {
    uint_t b = __float_as_uint(f);
    b += 0x7FFFu + ((b >> 16) & 1u);   // RNE to bf16
    return (ushort_t)(b >> 16);
}

#define BB 4
#define CK 64
#define NN 8192
#define MM 1024
#define CV 512
#define NSTEP 128     // 64-token steps over full n-range

// ---- module-scope scratch (fully rewritten every call) ----
__device__ __align__(16) ushort_t g_mkT[BB * NN * CK];   // 4 MiB  bf16 mk^T [b][n][c]
__device__ __align__(16) float    g_asq8[BB * NN];       // 128 KiB (sum mk^2)/8
__device__ __align__(16) ushort_t g_mvb[BB * CV * NN];   // 32 MiB bf16 mv [b][c][n]

// ---------------------------------------------------------------------------
// K0: g_mkT[b][n][c] = bf16(mk[b][c][n]); g_asq8 = (sum_c mk^2)/8 in fp32.
// ---------------------------------------------------------------------------
__global__ __launch_bounds__(256) void k_prep(const float* __restrict__ mk) {
    int t = blockIdx.x * 256 + threadIdx.x;   // 0 .. B*N-1
    int b = t >> 13;
    int n = t & (NN - 1);
    const float* src = mk + (size_t)b * CK * NN + n;
    ushort_t* dst = g_mkT + (size_t)t * CK;
    float acc = 0.f;
#pragma unroll
    for (int g = 0; g < 8; g++) {
        float f[8];
#pragma unroll
        for (int i = 0; i < 8; i++) {
            f[i] = src[(size_t)(g * 8 + i) * NN];
            acc += f[i] * f[i];
        }
        uint4 q;
        q.x = (uint_t)f2b(f[0]) | ((uint_t)f2b(f[1]) << 16);
        q.y = (uint_t)f2b(f[2]) | ((uint_t)f2b(f[3]) << 16);
        q.z = (uint_t)f2b(f[4]) | ((uint_t)f2b(f[5]) << 16);
        q.w = (uint_t)f2b(f[6]) | ((uint_t)f2b(f[7]) << 16);
        *(uint4*)(dst + g * 8) = q;
    }
    g_asq8[t] = acc * 0.125f;
}

// ---------------------------------------------------------------------------
// K0b: g_mvb = bf16(mv), flat, 8 elems/thread.
// ---------------------------------------------------------------------------
__global__ __launch_bounds__(256) void k_mvconv(const float* __restrict__ mv) {
    size_t t = (size_t)blockIdx.x * 256 + threadIdx.x;
    const float4* s = (const float4*)mv + t * 2;
    float4 x = s[0], y = s[1];
    uint4 q;
    q.x = (uint_t)f2b(x.x) | ((uint_t)f2b(x.y) << 16);
    q.y = (uint_t)f2b(x.z) | ((uint_t)f2b(x.w) << 16);
    q.z = (uint_t)f2b(y.x) | ((uint_t)f2b(y.y) << 16);
    q.w = (uint_t)f2b(y.z) | ((uint_t)f2b(y.w) << 16);
    ((uint4*)g_mvb)[t] = q;
}

// ---------------------------------------------------------------------------
// K1: fused everything. grid 512 = mt16(16) x cs(8) x b(4), bx = mt16*32+cs*4+b
// -> bx%8 = (cs*4+b)%8 constant per (b,cs): all 16 mt-blocks of a group on one
// XCD, streaming the same mkT[b]/mv-slice windows in lockstep (R6's 27MB-FETCH
// behavior). 2 blocks/CU = 8 waves/CU.
// Per 64-token step: GEMM1 (Q-frags in regs x K-frags from LDS ktile) -> exp ->
// P bf16 to LDS + denom partial; barrier; prefetch next ktile (async, drains at
// step-end barrier); GEMM2 (mv direct 16B loads x P from LDS) -> acc; barrier.
// Epilogue: in-block denom exchange, divide, store fp32.
// MFMA layouts (m89/m91): A[row=lane&15][k=quad*8+j], B same, D col=lane&15
// (B-row), row=quad*4+reg (A-row).
// ---------------------------------------------------------------------------
__global__ __launch_bounds__(256, 2) void k_main(const float* __restrict__ qk,
                                                 float* __restrict__ out) {
    // ktile chunk layout: 16B chunk (cq, n) at ushort offset (cq*64+n)*8.
    // ds_read_b128 banks: (l15*4+j)%32 -> 2-way (free). global_load_lds dst =
    // uniform base (cq*512 ushorts) + lane*16B, gaddr = row n0+lane chunk cq.
    __shared__ __align__(16) ushort_t ktile[2][64 * 64];   // 2 x 8 KiB
    __shared__ __align__(16) ushort_t lds_p[64 * 72];      // 9 KiB, pitch 72
    __shared__ __align__(16) float    asq_s[2][64];
    __shared__ float denom_s[64];

    int bx = blockIdx.x;
    int mt16 = bx >> 5;          // 0..15
    int cs = (bx >> 2) & 7;      // 0..7
    int b = bx & 3;              // 0..3
    int c0 = cs * 64;
    int m0 = mt16 * 64;

    int tid = threadIdx.x;
    int w = tid >> 6;
    int lane = tid & 63;
    int quad = lane >> 4;
    int l15 = lane & 15;

    // Q fragments (16 m-rows per wave, K=64), held in regs all loop.
    int mrow = m0 + w * 16 + l15;
    short8 aq0, aq1;
#pragma unroll
    for (int j = 0; j < 8; j++) {
        aq0[j] = (short)f2b(qk[(size_t)(b * CK + quad * 8 + j) * MM + mrow]);
        aq1[j] = (short)f2b(qk[(size_t)(b * CK + 32 + quad * 8 + j) * MM + mrow]);
    }

    const ushort_t* mkTb = g_mkT + (size_t)b * NN * CK;

    floatx4 acc[4];
#pragma unroll
    for (int j = 0; j < 4; j++) acc[j] = (floatx4){0.f, 0.f, 0.f, 0.f};
    float dpart[4] = {0.f, 0.f, 0.f, 0.f};
    int mbase = w * 16 + quad * 4;

    // ---- prologue: stage ktile[0] + asq[0] ----
    {
#pragma unroll
        for (int gi = 0; gi < 2; gi++) {
            int g2 = w + gi * 4;
            const ushort_t* gsrc = mkTb + (size_t)lane * CK + g2 * 8;
            ushort_t* ldst = &ktile[0][g2 * 512];
            __builtin_amdgcn_global_load_lds(
                (const __attribute__((address_space(1))) unsigned int*)gsrc,
                (__attribute__((address_space(3))) unsigned int*)ldst, 16, 0, 0);
        }
        if (w == 0) {
            const float* as = g_asq8 + (size_t)b * NN + lane;
            __builtin_amdgcn_global_load_lds(
                (const __attribute__((address_space(1))) unsigned int*)as,
                (__attribute__((address_space(3))) unsigned int*)&asq_s[0][0], 4, 0, 0);
        }
    }
    __syncthreads();   // vmcnt(0) drain -> ktile[0]/asq[0] ready

    for (int step = 0; step < NSTEP; step++) {
        int buf = step & 1;
        int n0 = step * 64;

        // ---- GEMM1: scores from LDS ktile -> exp -> P(bf16) to LDS ----
#pragma unroll
        for (int nt = 0; nt < 4; nt++) {
            int nl = nt * 16 + l15;
            const ushort_t* kr = &ktile[buf][(quad * 64 + nl) * 8];
            short8 kb0 = *(const short8*)kr;
            short8 kb1 = *(const short8*)(kr + 2048);   // cq+4
            floatx4 d = {0.f, 0.f, 0.f, 0.f};
            d = MFMA16(aq0, kb0, d);
            d = MFMA16(aq1, kb1, d);
            float sa = asq_s[buf][nl];
#pragma unroll
            for (int r = 0; r < 4; r++) {
                float p = __expf(d[r] * 0.25f - sa);
                dpart[r] += p;
                lds_p[(mbase + r) * 72 + nl] = f2b(p);
            }
        }
        __syncthreads();   // P ready

        // ---- prefetch next ktile (overlaps GEMM2; drains at step-end barrier)
        if (step + 1 < NSTEP) {
            int nb = buf ^ 1;
            int n1 = n0 + 64;
#pragma unroll
            for (int gi = 0; gi < 2; gi++) {
                int g2 = w + gi * 4;
                const ushort_t* gsrc = mkTb + (size_t)(n1 + lane) * CK + g2 * 8;
                ushort_t* ldst = &ktile[nb][g2 * 512];
                __builtin_amdgcn_global_load_lds(
                    (const __attribute__((address_space(1))) unsigned int*)gsrc,
                    (__attribute__((address_space(3))) unsigned int*)ldst, 16, 0, 0);
            }
            if (w == 0) {
                const float* as = g_asq8 + (size_t)b * NN + n1 + lane;
                __builtin_amdgcn_global_load_lds(
                    (const __attribute__((address_space(1))) unsigned int*)as,
                    (__attribute__((address_space(3))) unsigned int*)&asq_s[nb][0], 4, 0, 0);
            }
        }

        // ---- GEMM2: acc[c 16/wave][m 64] += mv-tile x P-tile ----
#pragma unroll
        for (int kc = 0; kc < 2; kc++) {
            short8 pb[4];
#pragma unroll
            for (int mt = 0; mt < 4; mt++)
                pb[mt] = *(const short8*)&lds_p[(mt * 16 + l15) * 72 + kc * 32 + quad * 8];
            size_t vidx = (size_t)(b * CV + c0 + w * 16 + l15) * NN + n0 + kc * 32 + quad * 8;
            short8 va = *(const short8*)(g_mvb + vidx);
#pragma unroll
            for (int mt = 0; mt < 4; mt++)
                acc[mt] = MFMA16(va, pb[mt], acc[mt]);
        }
        __syncthreads();   // P consumed; vmcnt(0) -> next ktile landed
    }

    // ---- epilogue: in-block denominator exchange, normalize, store fp32 ----
#pragma unroll
    for (int off = 1; off < 16; off <<= 1) {
#pragma unroll
        for (int r = 0; r < 4; r++) dpart[r] += __shfl_xor(dpart[r], off, 64);
    }
    if (l15 == 0) {
#pragma unroll
        for (int r = 0; r < 4; r++) denom_s[w * 16 + quad * 4 + r] = dpart[r];
    }
    __syncthreads();

#pragma unroll
    for (int mt = 0; mt < 4; mt++) {
        float rdm = 1.0f / denom_s[mt * 16 + l15];
#pragma unroll
        for (int r = 0; r < 4; r++) {
            size_t o = (size_t)(b * CV + c0 + w * 16 + quad * 4 + r) * MM + m0 + mt * 16 + l15;
            out[o] = acc[mt][r] * rdm;
        }
    }
}

// ---------------------------------------------------------------------------
// launch — inputs identified BY SIZE.
// ---------------------------------------------------------------------------
extern "C" void kernel_launch(void* const* d_in, const int* in_sizes, int n_in,
                              void* d_out, int out_size, void* d_ws, size_t ws_size,
                              hipStream_t stream) {
    const float* mk = nullptr;   // 2,097,152
    const float* qk = nullptr;   //   262,144
    const float* mv = nullptr;   // 16,777,216
    for (int i = 0; i < n_in; i++) {
        if (in_sizes[i] == BB * CK * NN)      mk = (const float*)d_in[i];
        else if (in_sizes[i] == BB * CK * MM) qk = (const float*)d_in[i];
        else if (in_sizes[i] == BB * CV * NN) mv = (const float*)d_in[i];
    }
    float* out = (float*)d_out;
    (void)d_ws; (void)ws_size; (void)out_size;

    const size_t mv_elems = (size_t)BB * CV * NN;

    k_prep<<<(BB * NN) / 256, 256, 0, stream>>>(mk);
    k_mvconv<<<(int)(mv_elems / (8 * 256)), 256, 0, stream>>>(mv);
    k_main<<<16 * 8 * BB, 256, 0, stream>>>(qk, out);
}